// Round 1
// baseline (722.276 us; speedup 1.0000x reference)
//
#include <hip/hip_runtime.h>
#include <math.h>

#define NTOK 16384
#define HDIM 2048
#define KNOI 25
#define RPW 4   // rows per wave
#define WPB 4   // waves per block (block = 256 threads)

// One wave handles RPW=4 consecutive rows. Per H-chunk of 256 floats each lane
// loads float4 per row (input + target row) + 25 noise-row float4s (L1-hot,
// 200 KB shared working set). 104 fp32 accumulators/lane, butterfly-reduced.
__global__ __launch_bounds__(256) void nce_main(
    const float* __restrict__ input,
    const float* __restrict__ weight,
    const float* __restrict__ bias,
    const float* __restrict__ uni,
    const int* __restrict__ target,
    const int* __restrict__ noise,
    float* __restrict__ out)
{
    float* pmt = out;
    float* pnt = out + NTOK;
    float* pmn = out + 2 * NTOK;
    float* pnn = out + 2 * NTOK + NTOK * KNOI;

    const int lane = threadIdx.x & 63;
    const int wave = threadIdx.x >> 6;
    int row0 = (blockIdx.x * WPB + wave) * RPW;
    row0 = __builtin_amdgcn_readfirstlane(row0);   // force SGPR (wave-uniform)

    // Uniform noise metadata -> scalar loads / SGPRs. Byte offsets fit in u32
    // (50257*8192 = 412 MB < 2^32).
    unsigned noffb[KNOI];
    float nbias[KNOI], nuni[KNOI];
#pragma unroll
    for (int k = 0; k < KNOI; ++k) {
        const int nk = noise[k];
        noffb[k] = (unsigned)nk * (unsigned)(HDIM * 4);
        nbias[k] = bias[nk];
        nuni[k]  = uni[nk];
    }

    unsigned toffb[RPW], ioffb[RPW];
    float tbias[RPW], tuni[RPW];
#pragma unroll
    for (int r = 0; r < RPW; ++r) {
        const int tk = target[row0 + r];
        toffb[r] = (unsigned)tk * (unsigned)(HDIM * 4);
        ioffb[r] = (unsigned)(row0 + r) * (unsigned)(HDIM * 4);
        tbias[r] = bias[tk];
        tuni[r]  = uni[tk];
    }

    const char* wb = (const char*)weight;
    const char* ib = (const char*)input;

    float acc[RPW][KNOI];
    float acct[RPW];
#pragma unroll
    for (int r = 0; r < RPW; ++r) {
        acct[r] = 0.f;
#pragma unroll
        for (int k = 0; k < KNOI; ++k) acc[r][k] = 0.f;
    }

    // H = 2048 floats = 8 chunks of 256 floats (one float4 per lane per row).
#pragma unroll 2
    for (int c = 0; c < HDIM / 256; ++c) {
        const unsigned offb = (unsigned)(c * 1024 + lane * 16);   // bytes
        float4 in[RPW];
#pragma unroll
        for (int r = 0; r < RPW; ++r)
            in[r] = *(const float4*)(ib + (ioffb[r] + offb));
#pragma unroll
        for (int r = 0; r < RPW; ++r) {
            const float4 w = *(const float4*)(wb + (toffb[r] + offb));
            acct[r] += in[r].x * w.x + in[r].y * w.y + in[r].z * w.z + in[r].w * w.w;
        }
#pragma unroll
        for (int k = 0; k < KNOI; ++k) {
            const float4 w = *(const float4*)(wb + (noffb[k] + offb));
#pragma unroll
            for (int r = 0; r < RPW; ++r)
                acc[r][k] += in[r].x * w.x + in[r].y * w.y + in[r].z * w.z + in[r].w * w.w;
        }
    }

    // Butterfly reduce each accumulator across the 64-lane wave.
#pragma unroll
    for (int r = 0; r < RPW; ++r) {
#pragma unroll
        for (int m = 32; m >= 1; m >>= 1)
            acct[r] += __shfl_xor(acct[r], m, 64);
#pragma unroll
        for (int k = 0; k < KNOI; ++k) {
#pragma unroll
            for (int m = 32; m >= 1; m >>= 1)
                acc[r][k] += __shfl_xor(acc[r][k], m, 64);
        }
    }

    // exp computed redundantly in all lanes (SIMD-free vs. divergent tail).
    float pv[RPW];
#pragma unroll
    for (int r = 0; r < RPW; ++r) {
        pv[r] = expf(acct[r] + tbias[r]);
#pragma unroll
        for (int k = 0; k < KNOI; ++k)
            acc[r][k] = expf(acc[r][k] + nbias[k]);
    }

    // Lane r stores row r's outputs (values identical in all lanes post-butterfly).
#pragma unroll
    for (int r = 0; r < RPW; ++r) {
        if (lane == r) {
            const int row = row0 + r;
            pmt[row] = pv[r];
            pnt[row] = tuni[r];
#pragma unroll
            for (int k = 0; k < KNOI; ++k) {
                pmn[row * KNOI + k] = acc[r][k];
                pnn[row * KNOI + k] = nuni[k];
            }
        }
    }
}

extern "C" void kernel_launch(void* const* d_in, const int* in_sizes, int n_in,
                              void* d_out, int out_size, void* d_ws, size_t ws_size,
                              hipStream_t stream) {
    const float* input  = (const float*)d_in[0];
    const float* weight = (const float*)d_in[1];
    const float* bias   = (const float*)d_in[2];
    const float* uni    = (const float*)d_in[3];
    const int*   target = (const int*)d_in[4];
    const int*   noise  = (const int*)d_in[5];
    float* out = (float*)d_out;

    const dim3 grid(NTOK / (WPB * RPW));   // 1024 blocks
    const dim3 block(256);
    hipLaunchKernelGGL(nce_main, grid, block, 0, stream,
                       input, weight, bias, uni, target, noise, out);
}

// Round 2
// 577.078 us; speedup vs baseline: 1.2516x; 1.2516x over previous
//
#include <hip/hip_runtime.h>
#include <math.h>

#define NTOK 16384
#define HDIM 2048
#define KNOI 25
#define RPW  2            // rows per wave
#define WPB  4            // waves per block (256 threads)
#define CHUNK 256         // floats of H per chunk
#define NCHUNK (HDIM / CHUNK)   // 8

typedef __attribute__((address_space(3))) unsigned lds_uint;
typedef __attribute__((address_space(1))) const unsigned glob_uint;

// Async global->LDS, 16B per lane, dest = uniform base + lane*16 (HW rule).
__device__ __forceinline__ void stage16(const void* g, void* l) {
    __builtin_amdgcn_global_load_lds((glob_uint*)g, (lds_uint*)l, 16, 0, 0);
}

// Block: 4 waves x 2 rows = 8 token rows. Per H-chunk (256 floats):
//  - block cooperatively stages the 25 noise-row chunks (25.6 KB) into LDS via
//    global_load_lds (zero VGPR cost, off the per-wave L1 path),
//  - each lane loads 2 input + 2 target float4 from global (prefetched one
//    chunk ahead), reads 25 LDS float4s, does 104 fp32 FMAs.
// 52 accumulators/lane; __launch_bounds__(256,4) caps VGPR<=128 -> 4 waves/SIMD.
__global__ __launch_bounds__(256, 4) void nce_main(
    const float* __restrict__ input,
    const float* __restrict__ weight,
    const float* __restrict__ bias,
    const float* __restrict__ uni,
    const int* __restrict__ target,
    const int* __restrict__ noise,
    float* __restrict__ out)
{
    __shared__ float4 ldsn[KNOI * (CHUNK / 4)];   // 25 rows x 1KB = 25.6 KB

    float* pmt = out;
    float* pnt = out + NTOK;
    float* pmn = out + 2 * NTOK;
    float* pnn = out + 2 * NTOK + NTOK * KNOI;

    const int lane = threadIdx.x & 63;
    const int wave = threadIdx.x >> 6;
    int row0 = (blockIdx.x * WPB + wave) * RPW;
    row0 = __builtin_amdgcn_readfirstlane(row0);   // wave-uniform -> SGPR

    // Noise byte offsets only (uniform -> SGPRs). bias/uni gathers deferred to
    // epilogue to keep SGPR/VGPR pressure off the main loop.
    unsigned noffb[KNOI];
#pragma unroll
    for (int k = 0; k < KNOI; ++k)
        noffb[k] = (unsigned)noise[k] * (unsigned)(HDIM * 4);

    unsigned toffb[RPW], ioffb[RPW];
#pragma unroll
    for (int r = 0; r < RPW; ++r) {
        toffb[r] = (unsigned)target[row0 + r] * (unsigned)(HDIM * 4);
        ioffb[r] = (unsigned)(row0 + r) * (unsigned)(HDIM * 4);
    }

    const char* wb = (const char*)weight;
    const char* ib = (const char*)input;
    const unsigned laneoff = (unsigned)lane * 16u;

    float acc[RPW][KNOI];
    float acct[RPW];
#pragma unroll
    for (int r = 0; r < RPW; ++r) {
        acct[r] = 0.f;
#pragma unroll
        for (int k = 0; k < KNOI; ++k) acc[r][k] = 0.f;
    }

    // Prefetch chunk 0's input/target float4s.
    float4 inv[RPW], tgv[RPW];
#pragma unroll
    for (int r = 0; r < RPW; ++r) {
        inv[r] = *(const float4*)(ib + ioffb[r] + laneoff);
        tgv[r] = *(const float4*)(wb + toffb[r] + laneoff);
    }

    for (int c = 0; c < NCHUNK; ++c) {
        const unsigned cb = (unsigned)c * (unsigned)(CHUNK * 4);

        // Stage noise chunk: wave w loads rows k = j*4+w (one 1KB row-chunk
        // per wave-iteration; wave-uniform branch).
#pragma unroll
        for (int j = 0; j < 7; ++j) {
            const int k = j * WPB + wave;
            if (k < KNOI)
                stage16(wb + noffb[k] + cb + laneoff, &ldsn[k * (CHUNK / 4)]);
        }
        __syncthreads();   // drains staging (vmcnt) + makes LDS visible

        // Snapshot current chunk's in/target, then prefetch next chunk's.
        const float4 in0 = inv[0], in1 = inv[1];
        const float4 tg0 = tgv[0], tg1 = tgv[1];
        const unsigned nb = (unsigned)((c + 1) & (NCHUNK - 1)) * (unsigned)(CHUNK * 4);
#pragma unroll
        for (int r = 0; r < RPW; ++r) {
            inv[r] = *(const float4*)(ib + ioffb[r] + nb + laneoff);
            tgv[r] = *(const float4*)(wb + toffb[r] + nb + laneoff);
        }

#pragma unroll
        for (int k = 0; k < KNOI; ++k) {
            const float4 w = ldsn[k * (CHUNK / 4) + lane];   // ds_read_b128
            acc[0][k] += in0.x * w.x + in0.y * w.y + in0.z * w.z + in0.w * w.w;
            acc[1][k] += in1.x * w.x + in1.y * w.y + in1.z * w.z + in1.w * w.w;
        }
        acct[0] += in0.x * tg0.x + in0.y * tg0.y + in0.z * tg0.z + in0.w * tg0.w;
        acct[1] += in1.x * tg1.x + in1.y * tg1.y + in1.z * tg1.z + in1.w * tg1.w;

        __syncthreads();   // protect LDS before next chunk's staging
    }

    // Butterfly-reduce all 52 accumulators across the wave.
#pragma unroll
    for (int r = 0; r < RPW; ++r) {
#pragma unroll
        for (int m = 32; m >= 1; m >>= 1)
            acct[r] += __shfl_xor(acct[r], m, 64);
#pragma unroll
        for (int k = 0; k < KNOI; ++k) {
#pragma unroll
            for (int m = 32; m >= 1; m >>= 1)
                acc[r][k] += __shfl_xor(acc[r][k], m, 64);
        }
    }

    // Epilogue: lane r stores row r. Recover word indices from byte offsets
    // (off = idx * 8192 -> idx = off >> 13); gather bias/uni here, once.
#pragma unroll
    for (int r = 0; r < RPW; ++r) {
        if (lane == r) {
            const int row = row0 + r;
            const int tk = (int)(toffb[r] >> 13);
            pmt[row] = expf(acct[r] + bias[tk]);
            pnt[row] = uni[tk];
#pragma unroll
            for (int k = 0; k < KNOI; ++k) {
                const int nk = (int)(noffb[k] >> 13);
                pmn[row * KNOI + k] = expf(acc[r][k] + bias[nk]);
                pnn[row * KNOI + k] = uni[nk];
            }
        }
    }
}

extern "C" void kernel_launch(void* const* d_in, const int* in_sizes, int n_in,
                              void* d_out, int out_size, void* d_ws, size_t ws_size,
                              hipStream_t stream) {
    const float* input  = (const float*)d_in[0];
    const float* weight = (const float*)d_in[1];
    const float* bias   = (const float*)d_in[2];
    const float* uni    = (const float*)d_in[3];
    const int*   target = (const int*)d_in[4];
    const int*   noise  = (const int*)d_in[5];
    float* out = (float*)d_out;

    const dim3 grid(NTOK / (WPB * RPW));   // 2048 blocks
    const dim3 block(256);
    hipLaunchKernelGGL(nce_main, grid, block, 0, stream,
                       input, weight, bias, uni, target, noise, out);
}